// Round 5
// baseline (1396.851 us; speedup 1.0000x reference)
//
#include <hip/hip_runtime.h>

constexpr int NPIX = 196608;
constexpr int FF   = 32;
constexpr size_t SLOT = (size_t)NPIX * FF;   // elems per chain slot (grouped [4][N][8])

typedef short bf16x8 __attribute__((ext_vector_type(8)));
typedef float f32x4  __attribute__((ext_vector_type(4)));
typedef int   i32x4  __attribute__((ext_vector_type(4)));
typedef uint  u32x4  __attribute__((ext_vector_type(4)));

__device__ __forceinline__ float blo(uint u) {
    union { float f; uint i; } v; v.i = u << 16; return v.f;
}
__device__ __forceinline__ float bhi(uint u) {
    union { float f; uint i; } v; v.i = u & 0xffff0000u; return v.f;
}
__device__ __forceinline__ ushort f2b(float f) {
    union { float f; uint i; } v; v.f = f;
    uint r = v.i + 0x7fffu + ((v.i >> 16) & 1u);   // RNE
    return (ushort)(r >> 16);
}
__device__ __forceinline__ uint pack2(float lo, float hi) {
    return ((uint)f2b(hi) << 16) | (uint)f2b(lo);
}

// ---- maps [N][32] f32 -> grouped bf16 [4][N][8] ----
__global__ __launch_bounds__(256) void regroup_f2b(const float* __restrict__ src,
                                                   ushort* __restrict__ dst) {
    int t = blockIdx.x * 256 + threadIdx.x;
    int n = t >> 2, g = t & 3;
    const f32x4* sp = reinterpret_cast<const f32x4*>(src + (size_t)n * FF + g * 8);
    f32x4 a = sp[0], b = sp[1];
    u32x4 o;
    o.x = pack2(a.x, a.y); o.y = pack2(a.z, a.w);
    o.z = pack2(b.x, b.y); o.w = pack2(b.z, b.w);
    reinterpret_cast<u32x4*>(dst)[(size_t)g * NPIX + n] = o;
}

// ---- grouped Chebyshev step. group = blockIdx & 3 (XCD-affine under %8 rr).
// INIT: Tout = L(Tprev); else Tout = 2 L(Tprev) - Told.  T layout [4][N][8] bf16.
template<int NB, bool INIT>
__global__ __launch_bounds__(256, 4) void cheb_stepG(
    const ushort* __restrict__ Tprev,
    const ushort* __restrict__ Told,
    ushort*       __restrict__ Tout,
    const int*    __restrict__ idx,
    const float*  __restrict__ wnb)
{
    int b = blockIdx.x;
    int g = b & 3;
    int n = (b >> 2) * 256 + threadIdx.x;

    // streaming reads: nontemporal (protect gather set in L2)
    i32x4 I[NB / 4];
    f32x4 W[NB / 4];
    const i32x4* ip = reinterpret_cast<const i32x4*>(idx + (size_t)n * NB);
    const f32x4* wv = reinterpret_cast<const f32x4*>(wnb + (size_t)n * NB);
#pragma unroll
    for (int j = 0; j < NB / 4; ++j) {
        I[j] = __builtin_nontemporal_load(ip + j);
        W[j] = __builtin_nontemporal_load(wv + j);
    }

    const u32x4* Tp = reinterpret_cast<const u32x4*>(Tprev) + (size_t)g * NPIX;
    float s0 = 0.f, s1 = 0.f, s2 = 0.f, s3 = 0.f;
    float s4 = 0.f, s5 = 0.f, s6 = 0.f, s7 = 0.f;

#pragma unroll
    for (int j = 0; j < NB / 4; ++j) {
        i32x4 i4 = I[j]; f32x4 w4 = W[j];
#pragma unroll
        for (int e = 0; e < 4; ++e) {
            int   ii = (e == 0) ? i4.x : (e == 1) ? i4.y : (e == 2) ? i4.z : i4.w;
            float ww = (e == 0) ? w4.x : (e == 1) ? w4.y : (e == 2) ? w4.z : w4.w;
            u32x4 u = Tp[(size_t)ii];   // L2-local 16B gather
            s0 += ww * blo(u.x); s1 += ww * bhi(u.x);
            s2 += ww * blo(u.y); s3 += ww * bhi(u.y);
            s4 += ww * blo(u.z); s5 += ww * bhi(u.z);
            s6 += ww * blo(u.w); s7 += ww * bhi(u.w);
        }
    }

    size_t row = (size_t)g * NPIX + n;
    u32x4 o;
    if (INIT) {
        o.x = pack2(s0, s1); o.y = pack2(s2, s3);
        o.z = pack2(s4, s5); o.w = pack2(s6, s7);
    } else {
        u32x4 told = __builtin_nontemporal_load(
            reinterpret_cast<const u32x4*>(Told) + row);
        o.x = pack2(2.f * s0 - blo(told.x), 2.f * s1 - bhi(told.x));
        o.y = pack2(2.f * s2 - blo(told.y), 2.f * s3 - bhi(told.y));
        o.z = pack2(2.f * s4 - blo(told.z), 2.f * s5 - bhi(told.z));
        o.w = pack2(2.f * s6 - blo(told.w), 2.f * s7 - bhi(told.w));
    }
    __builtin_nontemporal_store(o, reinterpret_cast<u32x4*>(Tout) + row);
}

// ----- finish: out = LN(relu([N,K*32] @ W2 + b)) (+resid). chain grouped [4][N][8]. -----
// W2[(k,f)][g] = wd[k][f][0]*wp[2f][g] + wd[k][f][1]*wp[2f+1][g], built in LDS (bf16^T).
template<int K, bool RESIDUAL, bool OUT_GROUPED_BF16>
__global__ __launch_bounds__(256, 4) void finish_gemm(
    const ushort* __restrict__ chain,  // K slots, each grouped [4][N][8]
    const float*  __restrict__ wd,     // [K][32][2]
    const float*  __restrict__ wp,     // [64][32]
    const float*  __restrict__ bias,
    const float*  __restrict__ gamma,
    const float*  __restrict__ beta,
    const float*  __restrict__ resid,  // fp32 maps [N][32] or nullptr
    void*         __restrict__ outp)   // grouped ushort* or fp32 [N][32]
{
    constexpr int KW = K * 32;
    constexpr int WSTRIDE = KW + 8;
    __shared__ float swp[64 * 33];
    __shared__ __align__(16) ushort sW[32][WSTRIDE];

    int tid = threadIdx.x;
    int wv = tid >> 6, l = tid & 63;
    int r = l & 15, hi = l >> 4;            // hi = feature group
    int nbase = blockIdx.x * 64 + wv * 16;

    // A prefetch: grouped layout keeps 16B/lane coalesced segments
    bf16x8 aF[K];
#pragma unroll
    for (int k = 0; k < K; ++k)
        aF[k] = *reinterpret_cast<const bf16x8*>(
            chain + (size_t)k * SLOT + ((size_t)hi * NPIX + (nbase + r)) * 8);

    for (int i = tid; i < 64 * 32; i += 256) {
        int u = i >> 5, gg = i & 31;
        swp[u * 33 + gg] = wp[i];
    }
    __syncthreads();

    for (int i = tid; i < 32 * KW; i += 256) {
        int gg = i / KW, kf = i - gg * KW;
        int f = kf & 31;
        float2 wdv = *reinterpret_cast<const float2*>(wd + (size_t)kf * 2);
        float w2 = wdv.x * swp[(2 * f) * 33 + gg] + wdv.y * swp[(2 * f + 1) * 33 + gg];
        sW[gg][kf] = f2b(w2);
    }
    __syncthreads();

    f32x4 acc0 = {0.f, 0.f, 0.f, 0.f};
    f32x4 acc1 = {0.f, 0.f, 0.f, 0.f};
#pragma unroll
    for (int k = 0; k < K; ++k) {
        bf16x8 b0 = *reinterpret_cast<const bf16x8*>(&sW[r][k * 32 + hi * 8]);
        bf16x8 b1 = *reinterpret_cast<const bf16x8*>(&sW[16 + r][k * 32 + hi * 8]);
        acc0 = __builtin_amdgcn_mfma_f32_16x16x32_bf16(aF[k], b0, acc0, 0, 0, 0);
        acc1 = __builtin_amdgcn_mfma_f32_16x16x32_bf16(aF[k], b1, acc1, 0, 0, 0);
    }

    float bias_lo = bias[r],  bias_hi = bias[16 + r];
    float gam_lo  = gamma[r], gam_hi  = gamma[16 + r];
    float bet_lo  = beta[r],  bet_hi  = beta[16 + r];

#pragma unroll
    for (int v = 0; v < 4; ++v) {
        acc0[v] = fmaxf(acc0[v] + bias_lo, 0.f);
        acc1[v] = fmaxf(acc1[v] + bias_hi, 0.f);
    }
#pragma unroll
    for (int v = 0; v < 4; ++v) {
        float s1 = acc0[v] + acc1[v];
        float s2 = acc0[v] * acc0[v] + acc1[v] * acc1[v];
#pragma unroll
        for (int m = 1; m < 16; m <<= 1) {
            s1 += __shfl_xor(s1, m);
            s2 += __shfl_xor(s2, m);
        }
        float mu  = s1 * (1.f / 32.f);
        float var = s2 * (1.f / 32.f) - mu * mu;
        float rs  = rsqrtf(var + 1e-6f);
        int n = nbase + hi * 4 + v;
        float z0 = (acc0[v] - mu) * rs * gam_lo + bet_lo;
        float z1 = (acc1[v] - mu) * rs * gam_hi + bet_hi;
        if (RESIDUAL) {
            z0 += resid[(size_t)n * FF + r];
            z1 += resid[(size_t)n * FF + 16 + r];
        }
        if (OUT_GROUPED_BF16) {
            ushort* op = (ushort*)outp;
            int f0 = r, f1 = 16 + r;
            op[((size_t)(f0 >> 3) * NPIX + n) * 8 + (f0 & 7)] = f2b(z0);
            op[((size_t)(f1 >> 3) * NPIX + n) * 8 + (f1 & 7)] = f2b(z1);
        } else {
            float* op = (float*)outp;
            op[(size_t)n * FF + r]      = z0;
            op[(size_t)n * FF + 16 + r] = z1;
        }
    }
}

extern "C" void kernel_launch(void* const* d_in, const int* in_sizes, int n_in,
                              void* d_out, int out_size, void* d_ws, size_t ws_size,
                              hipStream_t stream) {
    const float* maps = (const float*)d_in[0];
    const int*   idx1 = (const int*)  d_in[1];
    const float* w1nb = (const float*)d_in[2];
    const int*   idx2 = (const int*)  d_in[3];
    const float* w2nb = (const float*)d_in[4];
    const float* wd1  = (const float*)d_in[5];
    const float* wp1  = (const float*)d_in[6];
    const float* b1   = (const float*)d_in[7];
    const float* g1   = (const float*)d_in[8];
    const float* be1  = (const float*)d_in[9];
    const float* wd2  = (const float*)d_in[10];
    const float* wp2  = (const float*)d_in[11];
    const float* b2   = (const float*)d_in[12];
    const float* g2   = (const float*)d_in[13];
    const float* be2  = (const float*)d_in[14];
    float* out = (float*)d_out;

    // ws: 10 grouped bf16 slots (120 MiB). Layer-2 chain B0..B9 = slots 0..9;
    // layer-1 chain A0..A5 = slots 4..9 (consumed by finish1 before overwrite).
    ushort* slots = (ushort*)d_ws;
    ushort* B = slots;
    ushort* A = slots + 4 * SLOT;

    const int stepBlocks = NPIX * 4 / 256;   // 3072 (4 feature groups)
    const int finBlocks  = NPIX / 64;        // 3072

    // ---------------- layer 1: K=6, NB=8 ----------------
    regroup_f2b<<<stepBlocks, 256, 0, stream>>>(maps, A);                                   // A0
    cheb_stepG<8, true><<<stepBlocks, 256, 0, stream>>>(A, nullptr, A + SLOT, idx1, w1nb);  // A1
    cheb_stepG<8, false><<<stepBlocks, 256, 0, stream>>>(A + SLOT,     A,              A + 2 * SLOT, idx1, w1nb);
    cheb_stepG<8, false><<<stepBlocks, 256, 0, stream>>>(A + 2 * SLOT, A + SLOT,       A + 3 * SLOT, idx1, w1nb);
    cheb_stepG<8, false><<<stepBlocks, 256, 0, stream>>>(A + 3 * SLOT, A + 2 * SLOT,   A + 4 * SLOT, idx1, w1nb);
    cheb_stepG<8, false><<<stepBlocks, 256, 0, stream>>>(A + 4 * SLOT, A + 3 * SLOT,   A + 5 * SLOT, idx1, w1nb);
    finish_gemm<6, false, true><<<finBlocks, 256, 0, stream>>>(A, wd1, wp1, b1, g1, be1, nullptr, B);  // -> B0

    // ---------------- layer 2: K=10, NB=20 ----------------
    cheb_stepG<20, true><<<stepBlocks, 256, 0, stream>>>(B, nullptr, B + SLOT, idx2, w2nb); // B1
    for (int k = 2; k <= 9; ++k)
        cheb_stepG<20, false><<<stepBlocks, 256, 0, stream>>>(
            B + (size_t)(k - 1) * SLOT, B + (size_t)(k - 2) * SLOT,
            B + (size_t)k * SLOT, idx2, w2nb);
    finish_gemm<10, true, false><<<finBlocks, 256, 0, stream>>>(B, wd2, wp2, b2, g2, be2, maps, out);
}

// Round 6
// 796.253 us; speedup vs baseline: 1.7543x; 1.7543x over previous
//
#include <hip/hip_runtime.h>

constexpr int NPIX = 196608;
constexpr int FF   = 32;
constexpr size_t SLOT = (size_t)NPIX * FF;

typedef short bf16x8 __attribute__((ext_vector_type(8)));
typedef float f32x4  __attribute__((ext_vector_type(4)));
typedef int   i32x4  __attribute__((ext_vector_type(4)));
typedef uint  u32x4  __attribute__((ext_vector_type(4)));

__device__ __forceinline__ float blo(uint u) {
    union { float f; uint i; } v; v.i = u << 16; return v.f;
}
__device__ __forceinline__ float bhi(uint u) {
    union { float f; uint i; } v; v.i = u & 0xffff0000u; return v.f;
}
__device__ __forceinline__ ushort f2b(float f) {
    union { float f; uint i; } v; v.f = f;
    uint r = v.i + 0x7fffu + ((v.i >> 16) & 1u);   // RNE
    return (ushort)(r >> 16);
}
__device__ __forceinline__ uint pack2(float lo, float hi) {
    return ((uint)f2b(hi) << 16) | (uint)f2b(lo);
}

// ---------------- fp32 -> bf16 convert (maps -> chain T0) ----------------
__global__ __launch_bounds__(256) void f2b_kernel(const float* __restrict__ src,
                                                  ushort* __restrict__ dst) {
    int i = (blockIdx.x * 256 + threadIdx.x) * 4;
    f32x4 v = __builtin_nontemporal_load(reinterpret_cast<const f32x4*>(src + i));
    ushort4 o;
    o.x = f2b(v.x); o.y = f2b(v.y); o.z = f2b(v.z); o.w = f2b(v.w);
    *reinterpret_cast<ushort4*>(dst + i) = o;
}

// ------- Chebyshev step: 4 lanes/node, uint4 (8-feature) gathers, 1KB/instr -------
// Streams (idx, wnb, Told, Tout) nontemporal to protect the gather set in L2.
// INIT: Tout = L(Tprev).  else: Tout = 2 L(Tprev) - Told.
template<int NB, bool INIT>
__global__ __launch_bounds__(256, 4) void cheb_step4(
    const ushort* __restrict__ Tprev,
    const ushort* __restrict__ Told,
    ushort*       __restrict__ Tout,
    const int*    __restrict__ idx,
    const float*  __restrict__ wnb)
{
    int t = blockIdx.x * 256 + threadIdx.x;
    int n = t >> 2;          // node
    int h = t & 3;           // feature octet: features [h*8, h*8+8)

    const i32x4* ip = reinterpret_cast<const i32x4*>(idx + (size_t)n * NB);
    const f32x4* wv = reinterpret_cast<const f32x4*>(wnb + (size_t)n * NB);
    i32x4 I[NB / 4];
    f32x4 W[NB / 4];
#pragma unroll
    for (int j = 0; j < NB / 4; ++j) {
        I[j] = __builtin_nontemporal_load(ip + j);
        W[j] = __builtin_nontemporal_load(wv + j);
    }

    const u32x4* Tp = reinterpret_cast<const u32x4*>(Tprev);
    float s0 = 0.f, s1 = 0.f, s2 = 0.f, s3 = 0.f;
    float s4 = 0.f, s5 = 0.f, s6 = 0.f, s7 = 0.f;

#pragma unroll
    for (int j = 0; j < NB / 4; ++j) {
        i32x4 i4 = I[j]; f32x4 w4 = W[j];
#pragma unroll
        for (int e = 0; e < 4; ++e) {
            int   ii = (e == 0) ? i4.x : (e == 1) ? i4.y : (e == 2) ? i4.z : i4.w;
            float ww = (e == 0) ? w4.x : (e == 1) ? w4.y : (e == 2) ? w4.z : w4.w;
            u32x4 u = Tp[(size_t)ii * 4 + h];   // gather: normal load, L2-cached
            s0 += ww * blo(u.x); s1 += ww * bhi(u.x);
            s2 += ww * blo(u.y); s3 += ww * bhi(u.y);
            s4 += ww * blo(u.z); s5 += ww * bhi(u.z);
            s6 += ww * blo(u.w); s7 += ww * bhi(u.w);
        }
    }

    size_t base = (size_t)n * 4 + h;
    u32x4 o;
    if (INIT) {
        o.x = pack2(s0, s1); o.y = pack2(s2, s3);
        o.z = pack2(s4, s5); o.w = pack2(s6, s7);
    } else {
        u32x4 told = __builtin_nontemporal_load(
            reinterpret_cast<const u32x4*>(Told) + base);
        o.x = pack2(2.f * s0 - blo(told.x), 2.f * s1 - bhi(told.x));
        o.y = pack2(2.f * s2 - blo(told.y), 2.f * s3 - bhi(told.y));
        o.z = pack2(2.f * s4 - blo(told.z), 2.f * s5 - bhi(told.z));
        o.w = pack2(2.f * s6 - blo(told.w), 2.f * s7 - bhi(told.w));
    }
    __builtin_nontemporal_store(o, reinterpret_cast<u32x4*>(Tout) + base);
}

// ----- finish: out = LN(relu([N,K*32] @ W2 + b)) (+resid), W2 built in-block -----
// W2[(k,f)][g] = wd[k][f][0]*wp[2f][g] + wd[k][f][1]*wp[2f+1][g]; stored transposed
// in LDS as sW[g][k*32+f] (bf16, padded). A-frags load straight from global (nt).
template<int K, bool RESIDUAL, bool OUT_BF16>
__global__ __launch_bounds__(256, 4) void finish_gemm(
    const ushort* __restrict__ chain,  // K contiguous bf16 [N][32] slots
    const float*  __restrict__ wd,     // [K][32][2]
    const float*  __restrict__ wp,     // [64][32]
    const float*  __restrict__ bias,
    const float*  __restrict__ gamma,
    const float*  __restrict__ beta,
    const float*  __restrict__ resid,  // fp32 maps or nullptr
    void*         __restrict__ outp)   // ushort* (bf16) or float*
{
    constexpr int KW = K * 32;               // 192 or 320
    constexpr int WSTRIDE = KW + 8;          // ushort stride (16B pad)
    __shared__ float swp[64 * 33];
    __shared__ __align__(16) ushort sW[32][WSTRIDE];

    int tid = threadIdx.x;
    int wv = tid >> 6, l = tid & 63;
    int r = l & 15, hi = l >> 4;
    int nbase = blockIdx.x * 64 + wv * 16;

    // A prefetch: perfectly coalesced 16B/lane, read-once -> nontemporal
    bf16x8 aF[K];
#pragma unroll
    for (int k = 0; k < K; ++k)
        aF[k] = __builtin_nontemporal_load(reinterpret_cast<const bf16x8*>(
            chain + (size_t)k * SLOT + (size_t)(nbase + r) * FF + hi * 8));

    for (int i = tid; i < 64 * 32; i += 256) {
        int u = i >> 5, g = i & 31;
        swp[u * 33 + g] = wp[i];
    }
    __syncthreads();

    for (int i = tid; i < 32 * KW; i += 256) {
        int g = i / KW, kf = i - g * KW;
        int f = kf & 31;
        float2 wdv = *reinterpret_cast<const float2*>(wd + (size_t)kf * 2);
        float w2 = wdv.x * swp[(2 * f) * 33 + g] + wdv.y * swp[(2 * f + 1) * 33 + g];
        sW[g][kf] = f2b(w2);
    }
    __syncthreads();

    f32x4 acc0 = {0.f, 0.f, 0.f, 0.f};
    f32x4 acc1 = {0.f, 0.f, 0.f, 0.f};
#pragma unroll
    for (int k = 0; k < K; ++k) {
        bf16x8 b0 = *reinterpret_cast<const bf16x8*>(&sW[r][k * 32 + hi * 8]);
        bf16x8 b1 = *reinterpret_cast<const bf16x8*>(&sW[16 + r][k * 32 + hi * 8]);
        acc0 = __builtin_amdgcn_mfma_f32_16x16x32_bf16(aF[k], b0, acc0, 0, 0, 0);
        acc1 = __builtin_amdgcn_mfma_f32_16x16x32_bf16(aF[k], b1, acc1, 0, 0, 0);
    }

    float bias_lo = bias[r],  bias_hi = bias[16 + r];
    float gam_lo  = gamma[r], gam_hi  = gamma[16 + r];
    float bet_lo  = beta[r],  bet_hi  = beta[16 + r];

#pragma unroll
    for (int v = 0; v < 4; ++v) {
        acc0[v] = fmaxf(acc0[v] + bias_lo, 0.f);
        acc1[v] = fmaxf(acc1[v] + bias_hi, 0.f);
    }
#pragma unroll
    for (int v = 0; v < 4; ++v) {
        float s1 = acc0[v] + acc1[v];
        float s2 = acc0[v] * acc0[v] + acc1[v] * acc1[v];
#pragma unroll
        for (int m = 1; m < 16; m <<= 1) {
            s1 += __shfl_xor(s1, m);
            s2 += __shfl_xor(s2, m);
        }
        float mu  = s1 * (1.f / 32.f);
        float var = s2 * (1.f / 32.f) - mu * mu;
        float rs  = rsqrtf(var + 1e-6f);
        int n = nbase + hi * 4 + v;
        size_t o0 = (size_t)n * FF + r;
        size_t o1 = o0 + 16;
        float z0 = (acc0[v] - mu) * rs * gam_lo + bet_lo;
        float z1 = (acc1[v] - mu) * rs * gam_hi + bet_hi;
        if (RESIDUAL) { z0 += resid[o0]; z1 += resid[o1]; }
        if (OUT_BF16) {
            ((ushort*)outp)[o0] = f2b(z0);
            ((ushort*)outp)[o1] = f2b(z1);
        } else {
            ((float*)outp)[o0] = z0;
            ((float*)outp)[o1] = z1;
        }
    }
}

extern "C" void kernel_launch(void* const* d_in, const int* in_sizes, int n_in,
                              void* d_out, int out_size, void* d_ws, size_t ws_size,
                              hipStream_t stream) {
    const float* maps = (const float*)d_in[0];
    const int*   idx1 = (const int*)  d_in[1];
    const float* w1nb = (const float*)d_in[2];
    const int*   idx2 = (const int*)  d_in[3];
    const float* w2nb = (const float*)d_in[4];
    const float* wd1  = (const float*)d_in[5];
    const float* wp1  = (const float*)d_in[6];
    const float* b1   = (const float*)d_in[7];
    const float* g1   = (const float*)d_in[8];
    const float* be1  = (const float*)d_in[9];
    const float* wd2  = (const float*)d_in[10];
    const float* wp2  = (const float*)d_in[11];
    const float* b2   = (const float*)d_in[12];
    const float* g2   = (const float*)d_in[13];
    const float* be2  = (const float*)d_in[14];
    float* out = (float*)d_out;

    // ws: 10 bf16 slots (120 MiB). Layer-2 chain B0..B9 = slots 0..9;
    // layer-1 chain A0..A5 = slots 4..9 (consumed by finish1 before overwrite).
    ushort* slots = (ushort*)d_ws;
    ushort* B = slots;
    ushort* A = slots + 4 * SLOT;

    const int stepBlocks = NPIX * 4 / 256;        // 3072
    const int cvtBlocks  = NPIX * FF / (256 * 4); // 6144
    const int finBlocks  = NPIX / 64;             // 3072

    // ---------------- layer 1: K=6, NB=8 ----------------
    f2b_kernel<<<cvtBlocks, 256, 0, stream>>>(maps, A);                               // A0
    cheb_step4<8, true><<<stepBlocks, 256, 0, stream>>>(A, nullptr, A + SLOT, idx1, w1nb);  // A1
    cheb_step4<8, false><<<stepBlocks, 256, 0, stream>>>(A + SLOT,     A,              A + 2 * SLOT, idx1, w1nb);
    cheb_step4<8, false><<<stepBlocks, 256, 0, stream>>>(A + 2 * SLOT, A + SLOT,       A + 3 * SLOT, idx1, w1nb);
    cheb_step4<8, false><<<stepBlocks, 256, 0, stream>>>(A + 3 * SLOT, A + 2 * SLOT,   A + 4 * SLOT, idx1, w1nb);
    cheb_step4<8, false><<<stepBlocks, 256, 0, stream>>>(A + 4 * SLOT, A + 3 * SLOT,   A + 5 * SLOT, idx1, w1nb);
    finish_gemm<6, false, true><<<finBlocks, 256, 0, stream>>>(A, wd1, wp1, b1, g1, be1, nullptr, B);  // -> B0

    // ---------------- layer 2: K=10, NB=20 ----------------
    cheb_step4<20, true><<<stepBlocks, 256, 0, stream>>>(B, nullptr, B + SLOT, idx2, w2nb);  // B1
    for (int k = 2; k <= 9; ++k)
        cheb_step4<20, false><<<stepBlocks, 256, 0, stream>>>(
            B + (size_t)(k - 1) * SLOT, B + (size_t)(k - 2) * SLOT,
            B + (size_t)k * SLOT, idx2, w2nb);
    finish_gemm<10, true, false><<<finBlocks, 256, 0, stream>>>(B, wd2, wp2, b2, g2, be2, maps, out);
}

// Round 7
// 776.919 us; speedup vs baseline: 1.7979x; 1.0249x over previous
//
#include <hip/hip_runtime.h>

constexpr int NPIX = 196608;
constexpr int FF   = 32;
constexpr size_t SLOT = (size_t)NPIX * FF;

typedef short bf16x8 __attribute__((ext_vector_type(8)));
typedef float f32x4  __attribute__((ext_vector_type(4)));
typedef int   i32x4  __attribute__((ext_vector_type(4)));
typedef uint  u32x4  __attribute__((ext_vector_type(4)));

__device__ __forceinline__ float blo(uint u) {
    union { float f; uint i; } v; v.i = u << 16; return v.f;
}
__device__ __forceinline__ float bhi(uint u) {
    union { float f; uint i; } v; v.i = u & 0xffff0000u; return v.f;
}
__device__ __forceinline__ ushort f2b(float f) {
    union { float f; uint i; } v; v.f = f;
    uint r = v.i + 0x7fffu + ((v.i >> 16) & 1u);   // RNE
    return (ushort)(r >> 16);
}
__device__ __forceinline__ uint pack2(float lo, float hi) {
    return ((uint)f2b(hi) << 16) | (uint)f2b(lo);
}

// ---------------- fp32 -> bf16 convert (maps -> chain T0) ----------------
__global__ __launch_bounds__(256) void f2b_kernel(const float* __restrict__ src,
                                                  ushort* __restrict__ dst) {
    int i = (blockIdx.x * 256 + threadIdx.x) * 4;
    f32x4 v = *reinterpret_cast<const f32x4*>(src + i);
    ushort4 o;
    o.x = f2b(v.x); o.y = f2b(v.y); o.z = f2b(v.z); o.w = f2b(v.w);
    *reinterpret_cast<ushort4*>(dst + i) = o;
}

// ---- one-time: pack (idx,w) into ulong and sort each node's edges by src ----
template<int NB>
__global__ __launch_bounds__(256) void sort_edges(
    const int*   __restrict__ idx,
    const float* __restrict__ wnb,
    ulong*       __restrict__ edges)
{
    int n = blockIdx.x * 256 + threadIdx.x;
    ulong a[NB];
#pragma unroll
    for (int j = 0; j < NB; ++j) {
        union { float f; uint u; } w; w.f = wnb[(size_t)n * NB + j];
        a[j] = ((ulong)(uint)idx[(size_t)n * NB + j] << 32) | (ulong)w.u;
    }
    // odd-even transposition sort: NB rounds, fully static indices
#pragma unroll
    for (int r = 0; r < NB; ++r) {
#pragma unroll
        for (int i = (r & 1); i + 1 < NB; i += 2) {
            if (a[i] > a[i + 1]) { ulong t = a[i]; a[i] = a[i + 1]; a[i + 1] = t; }
        }
    }
#pragma unroll
    for (int j = 0; j < NB; ++j)
        edges[(size_t)n * NB + j] = a[j];
}

// ---- bucketed Chebyshev step: sweep sorted edges through src-range buckets ----
// All resident waves process bucket b at ~the same time -> gather window
// (NPIX/NBUCK rows * 64B) stays resident in each XCD's 4MB L2.
// INIT: Tout = L(Tprev). else: Tout = 2 L(Tprev) - Told.
template<int NB, int NBUCK, bool INIT>
__global__ __launch_bounds__(256, 4) void cheb_stepB(
    const ushort* __restrict__ Tprev,
    const ushort* __restrict__ Told,
    ushort*       __restrict__ Tout,
    const ulong*  __restrict__ edges)
{
    int t = blockIdx.x * 256 + threadIdx.x;
    int n = t >> 2;          // node
    int h = t & 3;           // feature octet

    const u32x4* Tp = reinterpret_cast<const u32x4*>(Tprev);
    size_t ebase = (size_t)n * NB;

    float s0 = 0.f, s1 = 0.f, s2 = 0.f, s3 = 0.f;
    float s4 = 0.f, s5 = 0.f, s6 = 0.f, s7 = 0.f;

    constexpr int BW = NPIX / NBUCK;
    constexpr ulong SENTINEL = 0x7FFFFFFF00000000ull;

    int p = 0;
    ulong e = edges[ebase];
#pragma unroll 1
    for (int b = 1; b <= NBUCK; ++b) {
        int frontier = b * BW;
        while ((int)(e >> 32) < frontier) {
            int src = (int)(e >> 32);
            union { float f; uint u; } wv; wv.u = (uint)e;
            float ww = wv.f;
            u32x4 u = Tp[(size_t)src * 4 + h];
            s0 += ww * blo(u.x); s1 += ww * bhi(u.x);
            s2 += ww * blo(u.y); s3 += ww * bhi(u.y);
            s4 += ww * blo(u.z); s5 += ww * bhi(u.z);
            s6 += ww * blo(u.w); s7 += ww * bhi(u.w);
            ++p;
            e = (p < NB) ? edges[ebase + p] : SENTINEL;
        }
    }

    size_t base = (size_t)n * 4 + h;
    u32x4 o;
    if (INIT) {
        o.x = pack2(s0, s1); o.y = pack2(s2, s3);
        o.z = pack2(s4, s5); o.w = pack2(s6, s7);
    } else {
        u32x4 told = reinterpret_cast<const u32x4*>(Told)[base];
        o.x = pack2(2.f * s0 - blo(told.x), 2.f * s1 - bhi(told.x));
        o.y = pack2(2.f * s2 - blo(told.y), 2.f * s3 - bhi(told.y));
        o.z = pack2(2.f * s4 - blo(told.z), 2.f * s5 - bhi(told.z));
        o.w = pack2(2.f * s6 - blo(told.w), 2.f * s7 - bhi(told.w));
    }
    reinterpret_cast<u32x4*>(Tout)[base] = o;
}

// ---- fallback (R4): unsorted 4-lane/node gather step ----
template<int NB, bool INIT>
__global__ __launch_bounds__(256, 4) void cheb_step4(
    const ushort* __restrict__ Tprev,
    const ushort* __restrict__ Told,
    ushort*       __restrict__ Tout,
    const int*    __restrict__ idx,
    const float*  __restrict__ wnb)
{
    int t = blockIdx.x * 256 + threadIdx.x;
    int n = t >> 2;
    int h = t & 3;

    const i32x4* ip = reinterpret_cast<const i32x4*>(idx + (size_t)n * NB);
    const f32x4* wv = reinterpret_cast<const f32x4*>(wnb + (size_t)n * NB);
    i32x4 I[NB / 4];
    f32x4 W[NB / 4];
#pragma unroll
    for (int j = 0; j < NB / 4; ++j) { I[j] = ip[j]; W[j] = wv[j]; }

    const u32x4* Tp = reinterpret_cast<const u32x4*>(Tprev);
    float s0 = 0.f, s1 = 0.f, s2 = 0.f, s3 = 0.f;
    float s4 = 0.f, s5 = 0.f, s6 = 0.f, s7 = 0.f;

#pragma unroll
    for (int j = 0; j < NB / 4; ++j) {
        i32x4 i4 = I[j]; f32x4 w4 = W[j];
#pragma unroll
        for (int e = 0; e < 4; ++e) {
            int   ii = (e == 0) ? i4.x : (e == 1) ? i4.y : (e == 2) ? i4.z : i4.w;
            float ww = (e == 0) ? w4.x : (e == 1) ? w4.y : (e == 2) ? w4.z : w4.w;
            u32x4 u = Tp[(size_t)ii * 4 + h];
            s0 += ww * blo(u.x); s1 += ww * bhi(u.x);
            s2 += ww * blo(u.y); s3 += ww * bhi(u.y);
            s4 += ww * blo(u.z); s5 += ww * bhi(u.z);
            s6 += ww * blo(u.w); s7 += ww * bhi(u.w);
        }
    }

    size_t base = (size_t)n * 4 + h;
    u32x4 o;
    if (INIT) {
        o.x = pack2(s0, s1); o.y = pack2(s2, s3);
        o.z = pack2(s4, s5); o.w = pack2(s6, s7);
    } else {
        u32x4 told = reinterpret_cast<const u32x4*>(Told)[base];
        o.x = pack2(2.f * s0 - blo(told.x), 2.f * s1 - bhi(told.x));
        o.y = pack2(2.f * s2 - blo(told.y), 2.f * s3 - bhi(told.y));
        o.z = pack2(2.f * s4 - blo(told.z), 2.f * s5 - bhi(told.z));
        o.w = pack2(2.f * s6 - blo(told.w), 2.f * s7 - bhi(told.w));
    }
    reinterpret_cast<u32x4*>(Tout)[base] = o;
}

// ----- finish: out = LN(relu([N,K*32] @ W2 + b)) (+resid), W2 built in-block -----
template<int K, bool RESIDUAL, bool OUT_BF16>
__global__ __launch_bounds__(256, 4) void finish_gemm(
    const ushort* __restrict__ chain,
    const float*  __restrict__ wd,     // [K][32][2]
    const float*  __restrict__ wp,     // [64][32]
    const float*  __restrict__ bias,
    const float*  __restrict__ gamma,
    const float*  __restrict__ beta,
    const float*  __restrict__ resid,
    void*         __restrict__ outp)
{
    constexpr int KW = K * 32;
    constexpr int WSTRIDE = KW + 8;
    __shared__ float swp[64 * 33];
    __shared__ __align__(16) ushort sW[32][WSTRIDE];

    int tid = threadIdx.x;
    int wv = tid >> 6, l = tid & 63;
    int r = l & 15, hi = l >> 4;
    int nbase = blockIdx.x * 64 + wv * 16;

    bf16x8 aF[K];
#pragma unroll
    for (int k = 0; k < K; ++k)
        aF[k] = *reinterpret_cast<const bf16x8*>(
            chain + (size_t)k * SLOT + (size_t)(nbase + r) * FF + hi * 8);

    for (int i = tid; i < 64 * 32; i += 256) {
        int u = i >> 5, g = i & 31;
        swp[u * 33 + g] = wp[i];
    }
    __syncthreads();

    for (int i = tid; i < 32 * KW; i += 256) {
        int g = i / KW, kf = i - g * KW;
        int f = kf & 31;
        float2 wdv = *reinterpret_cast<const float2*>(wd + (size_t)kf * 2);
        float w2 = wdv.x * swp[(2 * f) * 33 + g] + wdv.y * swp[(2 * f + 1) * 33 + g];
        sW[g][kf] = f2b(w2);
    }
    __syncthreads();

    f32x4 acc0 = {0.f, 0.f, 0.f, 0.f};
    f32x4 acc1 = {0.f, 0.f, 0.f, 0.f};
#pragma unroll
    for (int k = 0; k < K; ++k) {
        bf16x8 b0 = *reinterpret_cast<const bf16x8*>(&sW[r][k * 32 + hi * 8]);
        bf16x8 b1 = *reinterpret_cast<const bf16x8*>(&sW[16 + r][k * 32 + hi * 8]);
        acc0 = __builtin_amdgcn_mfma_f32_16x16x32_bf16(aF[k], b0, acc0, 0, 0, 0);
        acc1 = __builtin_amdgcn_mfma_f32_16x16x32_bf16(aF[k], b1, acc1, 0, 0, 0);
    }

    float bias_lo = bias[r],  bias_hi = bias[16 + r];
    float gam_lo  = gamma[r], gam_hi  = gamma[16 + r];
    float bet_lo  = beta[r],  bet_hi  = beta[16 + r];

#pragma unroll
    for (int v = 0; v < 4; ++v) {
        acc0[v] = fmaxf(acc0[v] + bias_lo, 0.f);
        acc1[v] = fmaxf(acc1[v] + bias_hi, 0.f);
    }
#pragma unroll
    for (int v = 0; v < 4; ++v) {
        float s1 = acc0[v] + acc1[v];
        float s2 = acc0[v] * acc0[v] + acc1[v] * acc1[v];
#pragma unroll
        for (int m = 1; m < 16; m <<= 1) {
            s1 += __shfl_xor(s1, m);
            s2 += __shfl_xor(s2, m);
        }
        float mu  = s1 * (1.f / 32.f);
        float var = s2 * (1.f / 32.f) - mu * mu;
        float rs  = rsqrtf(var + 1e-6f);
        int n = nbase + hi * 4 + v;
        size_t o0 = (size_t)n * FF + r;
        size_t o1 = o0 + 16;
        float z0 = (acc0[v] - mu) * rs * gam_lo + bet_lo;
        float z1 = (acc1[v] - mu) * rs * gam_hi + bet_hi;
        if (RESIDUAL) { z0 += resid[o0]; z1 += resid[o1]; }
        if (OUT_BF16) {
            ((ushort*)outp)[o0] = f2b(z0);
            ((ushort*)outp)[o1] = f2b(z1);
        } else {
            ((float*)outp)[o0] = z0;
            ((float*)outp)[o1] = z1;
        }
    }
}

extern "C" void kernel_launch(void* const* d_in, const int* in_sizes, int n_in,
                              void* d_out, int out_size, void* d_ws, size_t ws_size,
                              hipStream_t stream) {
    const float* maps = (const float*)d_in[0];
    const int*   idx1 = (const int*)  d_in[1];
    const float* w1nb = (const float*)d_in[2];
    const int*   idx2 = (const int*)  d_in[3];
    const float* w2nb = (const float*)d_in[4];
    const float* wd1  = (const float*)d_in[5];
    const float* wp1  = (const float*)d_in[6];
    const float* b1   = (const float*)d_in[7];
    const float* g1   = (const float*)d_in[8];
    const float* be1  = (const float*)d_in[9];
    const float* wd2  = (const float*)d_in[10];
    const float* wp2  = (const float*)d_in[11];
    const float* b2   = (const float*)d_in[12];
    const float* g2   = (const float*)d_in[13];
    const float* be2  = (const float*)d_in[14];
    float* out = (float*)d_out;

    // ws: 10 bf16 chain slots (125.8 MB) + sorted edge arrays (44 MB)
    ushort* slots = (ushort*)d_ws;
    ushort* B = slots;
    ushort* A = slots + 4 * SLOT;
    ulong* edges2 = (ulong*)(slots + 10 * SLOT);            // [N*20]
    ulong* edges1 = edges2 + (size_t)NPIX * 20;             // [N*8]

    const size_t needSorted = 10 * SLOT * 2 + (size_t)NPIX * 20 * 8 + (size_t)NPIX * 8 * 8;
    const bool useSorted = ws_size >= needSorted;

    const int stepBlocks = NPIX * 4 / 256;        // 3072
    const int cvtBlocks  = NPIX * FF / (256 * 4); // 6144
    const int finBlocks  = NPIX / 64;             // 3072
    const int sortBlocks = NPIX / 256;            // 768

    if (useSorted) {
        sort_edges<8><<<sortBlocks, 256, 0, stream>>>(idx1, w1nb, edges1);
        sort_edges<20><<<sortBlocks, 256, 0, stream>>>(idx2, w2nb, edges2);
    }

    // ---------------- layer 1: K=6, NB=8 ----------------
    f2b_kernel<<<cvtBlocks, 256, 0, stream>>>(maps, A);   // A0
    if (useSorted) {
        cheb_stepB<8, 8, true><<<stepBlocks, 256, 0, stream>>>(A, nullptr, A + SLOT, edges1);
        cheb_stepB<8, 8, false><<<stepBlocks, 256, 0, stream>>>(A + SLOT,     A,            A + 2 * SLOT, edges1);
        cheb_stepB<8, 8, false><<<stepBlocks, 256, 0, stream>>>(A + 2 * SLOT, A + SLOT,     A + 3 * SLOT, edges1);
        cheb_stepB<8, 8, false><<<stepBlocks, 256, 0, stream>>>(A + 3 * SLOT, A + 2 * SLOT, A + 4 * SLOT, edges1);
        cheb_stepB<8, 8, false><<<stepBlocks, 256, 0, stream>>>(A + 4 * SLOT, A + 3 * SLOT, A + 5 * SLOT, edges1);
    } else {
        cheb_step4<8, true><<<stepBlocks, 256, 0, stream>>>(A, nullptr, A + SLOT, idx1, w1nb);
        cheb_step4<8, false><<<stepBlocks, 256, 0, stream>>>(A + SLOT,     A,            A + 2 * SLOT, idx1, w1nb);
        cheb_step4<8, false><<<stepBlocks, 256, 0, stream>>>(A + 2 * SLOT, A + SLOT,     A + 3 * SLOT, idx1, w1nb);
        cheb_step4<8, false><<<stepBlocks, 256, 0, stream>>>(A + 3 * SLOT, A + 2 * SLOT, A + 4 * SLOT, idx1, w1nb);
        cheb_step4<8, false><<<stepBlocks, 256, 0, stream>>>(A + 4 * SLOT, A + 3 * SLOT, A + 5 * SLOT, idx1, w1nb);
    }
    finish_gemm<6, false, true><<<finBlocks, 256, 0, stream>>>(A, wd1, wp1, b1, g1, be1, nullptr, B);  // -> B0

    // ---------------- layer 2: K=10, NB=20 ----------------
    if (useSorted) {
        cheb_stepB<20, 12, true><<<stepBlocks, 256, 0, stream>>>(B, nullptr, B + SLOT, edges2);
        for (int k = 2; k <= 9; ++k)
            cheb_stepB<20, 12, false><<<stepBlocks, 256, 0, stream>>>(
                B + (size_t)(k - 1) * SLOT, B + (size_t)(k - 2) * SLOT,
                B + (size_t)k * SLOT, edges2);
    } else {
        cheb_step4<20, true><<<stepBlocks, 256, 0, stream>>>(B, nullptr, B + SLOT, idx2, w2nb);
        for (int k = 2; k <= 9; ++k)
            cheb_step4<20, false><<<stepBlocks, 256, 0, stream>>>(
                B + (size_t)(k - 1) * SLOT, B + (size_t)(k - 2) * SLOT,
                B + (size_t)k * SLOT, idx2, w2nb);
    }
    finish_gemm<10, true, false><<<finBlocks, 256, 0, stream>>>(B, wd2, wp2, b2, g2, be2, maps, out);
}

// Round 8
// 761.198 us; speedup vs baseline: 1.8351x; 1.0207x over previous
//
#include <hip/hip_runtime.h>

constexpr int NPIX = 196608;
constexpr int FF   = 32;
constexpr size_t SLOT = (size_t)NPIX * FF;

typedef short bf16x8 __attribute__((ext_vector_type(8)));
typedef float f32x4  __attribute__((ext_vector_type(4)));
typedef int   i32x4  __attribute__((ext_vector_type(4)));
typedef uint  u32x4  __attribute__((ext_vector_type(4)));

__device__ __forceinline__ float blo(uint u) {
    union { float f; uint i; } v; v.i = u << 16; return v.f;
}
__device__ __forceinline__ float bhi(uint u) {
    union { float f; uint i; } v; v.i = u & 0xffff0000u; return v.f;
}
__device__ __forceinline__ ushort f2b(float f) {
    union { float f; uint i; } v; v.f = f;
    uint r = v.i + 0x7fffu + ((v.i >> 16) & 1u);   // RNE
    return (ushort)(r >> 16);
}
__device__ __forceinline__ uint pack2(float lo, float hi) {
    return ((uint)f2b(hi) << 16) | (uint)f2b(lo);
}

// ---------------- fp32 -> bf16 convert (maps -> chain T0) ----------------
__global__ __launch_bounds__(256) void f2b_kernel(const float* __restrict__ src,
                                                  ushort* __restrict__ dst) {
    int i = (blockIdx.x * 256 + threadIdx.x) * 4;
    f32x4 v = *reinterpret_cast<const f32x4*>(src + i);
    ushort4 o;
    o.x = f2b(v.x); o.y = f2b(v.y); o.z = f2b(v.z); o.w = f2b(v.w);
    *reinterpret_cast<ushort4*>(dst + i) = o;
}

// ---- one-time: pack (idx,w) into ulong and sort each node's edges by src ----
template<int NB>
__global__ __launch_bounds__(256) void sort_edges(
    const int*   __restrict__ idx,
    const float* __restrict__ wnb,
    ulong*       __restrict__ edges)
{
    int n = blockIdx.x * 256 + threadIdx.x;
    ulong a[NB];
#pragma unroll
    for (int j = 0; j < NB; ++j) {
        union { float f; uint u; } w; w.f = wnb[(size_t)n * NB + j];
        a[j] = ((ulong)(uint)idx[(size_t)n * NB + j] << 32) | (ulong)w.u;
    }
#pragma unroll
    for (int r = 0; r < NB; ++r) {
#pragma unroll
        for (int i = (r & 1); i + 1 < NB; i += 2) {
            if (a[i] > a[i + 1]) { ulong t = a[i]; a[i] = a[i + 1]; a[i + 1] = t; }
        }
    }
#pragma unroll
    for (int j = 0; j < NB; ++j)
        edges[(size_t)n * NB + j] = a[j];
}

// ---- chunked-unrolled sorted sweep: ILP within chunk, temporal order across ----
// Edges sorted by src; chunks of CH edges processed in ascending order with a
// sched_barrier between chunks so all waves sweep sources low->high together
// (keeps each chunk's ~order-statistic window resident in per-XCD L2).
// INIT: Tout = L(Tprev). else: Tout = 2 L(Tprev) - Told.
template<int NB, int NCH, bool INIT>
__global__ __launch_bounds__(256, 4) void cheb_stepC(
    const ushort* __restrict__ Tprev,
    const ushort* __restrict__ Told,
    ushort*       __restrict__ Tout,
    const ulong*  __restrict__ edges)
{
    constexpr int CH = NB / NCH;
    int t = blockIdx.x * 256 + threadIdx.x;
    int n = t >> 2;          // node
    int h = t & 3;           // feature octet

    ulong E[NB];
    const ulong* ep = edges + (size_t)n * NB;
#pragma unroll
    for (int j = 0; j < NB; ++j) E[j] = ep[j];

    const u32x4* Tp = reinterpret_cast<const u32x4*>(Tprev);
    float s0 = 0.f, s1 = 0.f, s2 = 0.f, s3 = 0.f;
    float s4 = 0.f, s5 = 0.f, s6 = 0.f, s7 = 0.f;

#pragma unroll
    for (int c = 0; c < NCH; ++c) {
        u32x4 u[CH];
        float w[CH];
#pragma unroll
        for (int i = 0; i < CH; ++i) {
            ulong e = E[c * CH + i];
            union { float f; uint u; } wv; wv.u = (uint)e;
            w[i] = wv.f;
            u[i] = Tp[(size_t)(int)(e >> 32) * 4 + h];
        }
#pragma unroll
        for (int i = 0; i < CH; ++i) {
            s0 += w[i] * blo(u[i].x); s1 += w[i] * bhi(u[i].x);
            s2 += w[i] * blo(u[i].y); s3 += w[i] * bhi(u[i].y);
            s4 += w[i] * blo(u[i].z); s5 += w[i] * bhi(u[i].z);
            s6 += w[i] * blo(u[i].w); s7 += w[i] * bhi(u[i].w);
        }
        __builtin_amdgcn_sched_barrier(0);   // pin chunk ordering (temporal sweep)
    }

    size_t base = (size_t)n * 4 + h;
    u32x4 o;
    if (INIT) {
        o.x = pack2(s0, s1); o.y = pack2(s2, s3);
        o.z = pack2(s4, s5); o.w = pack2(s6, s7);
    } else {
        u32x4 told = reinterpret_cast<const u32x4*>(Told)[base];
        o.x = pack2(2.f * s0 - blo(told.x), 2.f * s1 - bhi(told.x));
        o.y = pack2(2.f * s2 - blo(told.y), 2.f * s3 - bhi(told.y));
        o.z = pack2(2.f * s4 - blo(told.z), 2.f * s5 - bhi(told.z));
        o.w = pack2(2.f * s6 - blo(told.w), 2.f * s7 - bhi(told.w));
    }
    reinterpret_cast<u32x4*>(Tout)[base] = o;
}

// ---- fallback (R4): unsorted 4-lane/node gather step ----
template<int NB, bool INIT>
__global__ __launch_bounds__(256, 4) void cheb_step4(
    const ushort* __restrict__ Tprev,
    const ushort* __restrict__ Told,
    ushort*       __restrict__ Tout,
    const int*    __restrict__ idx,
    const float*  __restrict__ wnb)
{
    int t = blockIdx.x * 256 + threadIdx.x;
    int n = t >> 2;
    int h = t & 3;

    const i32x4* ip = reinterpret_cast<const i32x4*>(idx + (size_t)n * NB);
    const f32x4* wv = reinterpret_cast<const f32x4*>(wnb + (size_t)n * NB);
    i32x4 I[NB / 4];
    f32x4 W[NB / 4];
#pragma unroll
    for (int j = 0; j < NB / 4; ++j) { I[j] = ip[j]; W[j] = wv[j]; }

    const u32x4* Tp = reinterpret_cast<const u32x4*>(Tprev);
    float s0 = 0.f, s1 = 0.f, s2 = 0.f, s3 = 0.f;
    float s4 = 0.f, s5 = 0.f, s6 = 0.f, s7 = 0.f;

#pragma unroll
    for (int j = 0; j < NB / 4; ++j) {
        i32x4 i4 = I[j]; f32x4 w4 = W[j];
#pragma unroll
        for (int e = 0; e < 4; ++e) {
            int   ii = (e == 0) ? i4.x : (e == 1) ? i4.y : (e == 2) ? i4.z : i4.w;
            float ww = (e == 0) ? w4.x : (e == 1) ? w4.y : (e == 2) ? w4.z : w4.w;
            u32x4 u = Tp[(size_t)ii * 4 + h];
            s0 += ww * blo(u.x); s1 += ww * bhi(u.x);
            s2 += ww * blo(u.y); s3 += ww * bhi(u.y);
            s4 += ww * blo(u.z); s5 += ww * bhi(u.z);
            s6 += ww * blo(u.w); s7 += ww * bhi(u.w);
        }
    }

    size_t base = (size_t)n * 4 + h;
    u32x4 o;
    if (INIT) {
        o.x = pack2(s0, s1); o.y = pack2(s2, s3);
        o.z = pack2(s4, s5); o.w = pack2(s6, s7);
    } else {
        u32x4 told = reinterpret_cast<const u32x4*>(Told)[base];
        o.x = pack2(2.f * s0 - blo(told.x), 2.f * s1 - bhi(told.x));
        o.y = pack2(2.f * s2 - blo(told.y), 2.f * s3 - bhi(told.y));
        o.z = pack2(2.f * s4 - blo(told.z), 2.f * s5 - bhi(told.z));
        o.w = pack2(2.f * s6 - blo(told.w), 2.f * s7 - bhi(told.w));
    }
    reinterpret_cast<u32x4*>(Tout)[base] = o;
}

// ----- finish: out = LN(relu([N,K*32] @ W2 + b)) (+resid), W2 built in-block -----
template<int K, bool RESIDUAL, bool OUT_BF16>
__global__ __launch_bounds__(256, 4) void finish_gemm(
    const ushort* __restrict__ chain,
    const float*  __restrict__ wd,     // [K][32][2]
    const float*  __restrict__ wp,     // [64][32]
    const float*  __restrict__ bias,
    const float*  __restrict__ gamma,
    const float*  __restrict__ beta,
    const float*  __restrict__ resid,
    void*         __restrict__ outp)
{
    constexpr int KW = K * 32;
    constexpr int WSTRIDE = KW + 8;
    __shared__ float swp[64 * 33];
    __shared__ __align__(16) ushort sW[32][WSTRIDE];

    int tid = threadIdx.x;
    int wv = tid >> 6, l = tid & 63;
    int r = l & 15, hi = l >> 4;
    int nbase = blockIdx.x * 64 + wv * 16;

    bf16x8 aF[K];
#pragma unroll
    for (int k = 0; k < K; ++k)
        aF[k] = *reinterpret_cast<const bf16x8*>(
            chain + (size_t)k * SLOT + (size_t)(nbase + r) * FF + hi * 8);

    for (int i = tid; i < 64 * 32; i += 256) {
        int u = i >> 5, g = i & 31;
        swp[u * 33 + g] = wp[i];
    }
    __syncthreads();

    for (int i = tid; i < 32 * KW; i += 256) {
        int g = i / KW, kf = i - g * KW;
        int f = kf & 31;
        float2 wdv = *reinterpret_cast<const float2*>(wd + (size_t)kf * 2);
        float w2 = wdv.x * swp[(2 * f) * 33 + g] + wdv.y * swp[(2 * f + 1) * 33 + g];
        sW[g][kf] = f2b(w2);
    }
    __syncthreads();

    f32x4 acc0 = {0.f, 0.f, 0.f, 0.f};
    f32x4 acc1 = {0.f, 0.f, 0.f, 0.f};
#pragma unroll
    for (int k = 0; k < K; ++k) {
        bf16x8 b0 = *reinterpret_cast<const bf16x8*>(&sW[r][k * 32 + hi * 8]);
        bf16x8 b1 = *reinterpret_cast<const bf16x8*>(&sW[16 + r][k * 32 + hi * 8]);
        acc0 = __builtin_amdgcn_mfma_f32_16x16x32_bf16(aF[k], b0, acc0, 0, 0, 0);
        acc1 = __builtin_amdgcn_mfma_f32_16x16x32_bf16(aF[k], b1, acc1, 0, 0, 0);
    }

    float bias_lo = bias[r],  bias_hi = bias[16 + r];
    float gam_lo  = gamma[r], gam_hi  = gamma[16 + r];
    float bet_lo  = beta[r],  bet_hi  = beta[16 + r];

#pragma unroll
    for (int v = 0; v < 4; ++v) {
        acc0[v] = fmaxf(acc0[v] + bias_lo, 0.f);
        acc1[v] = fmaxf(acc1[v] + bias_hi, 0.f);
    }
#pragma unroll
    for (int v = 0; v < 4; ++v) {
        float s1 = acc0[v] + acc1[v];
        float s2 = acc0[v] * acc0[v] + acc1[v] * acc1[v];
#pragma unroll
        for (int m = 1; m < 16; m <<= 1) {
            s1 += __shfl_xor(s1, m);
            s2 += __shfl_xor(s2, m);
        }
        float mu  = s1 * (1.f / 32.f);
        float var = s2 * (1.f / 32.f) - mu * mu;
        float rs  = rsqrtf(var + 1e-6f);
        int n = nbase + hi * 4 + v;
        size_t o0 = (size_t)n * FF + r;
        size_t o1 = o0 + 16;
        float z0 = (acc0[v] - mu) * rs * gam_lo + bet_lo;
        float z1 = (acc1[v] - mu) * rs * gam_hi + bet_hi;
        if (RESIDUAL) { z0 += resid[o0]; z1 += resid[o1]; }
        if (OUT_BF16) {
            ((ushort*)outp)[o0] = f2b(z0);
            ((ushort*)outp)[o1] = f2b(z1);
        } else {
            ((float*)outp)[o0] = z0;
            ((float*)outp)[o1] = z1;
        }
    }
}

extern "C" void kernel_launch(void* const* d_in, const int* in_sizes, int n_in,
                              void* d_out, int out_size, void* d_ws, size_t ws_size,
                              hipStream_t stream) {
    const float* maps = (const float*)d_in[0];
    const int*   idx1 = (const int*)  d_in[1];
    const float* w1nb = (const float*)d_in[2];
    const int*   idx2 = (const int*)  d_in[3];
    const float* w2nb = (const float*)d_in[4];
    const float* wd1  = (const float*)d_in[5];
    const float* wp1  = (const float*)d_in[6];
    const float* b1   = (const float*)d_in[7];
    const float* g1   = (const float*)d_in[8];
    const float* be1  = (const float*)d_in[9];
    const float* wd2  = (const float*)d_in[10];
    const float* wp2  = (const float*)d_in[11];
    const float* b2   = (const float*)d_in[12];
    const float* g2   = (const float*)d_in[13];
    const float* be2  = (const float*)d_in[14];
    float* out = (float*)d_out;

    // ws: 10 bf16 chain slots (125.8 MB) + sorted edge arrays (44 MB)
    ushort* slots = (ushort*)d_ws;
    ushort* B = slots;
    ushort* A = slots + 4 * SLOT;
    ulong* edges2 = (ulong*)(slots + 10 * SLOT);            // [N*20]
    ulong* edges1 = edges2 + (size_t)NPIX * 20;             // [N*8]

    const size_t needSorted = 10 * SLOT * 2 + (size_t)NPIX * 20 * 8 + (size_t)NPIX * 8 * 8;
    const bool useSorted = ws_size >= needSorted;

    const int stepBlocks = NPIX * 4 / 256;        // 3072
    const int cvtBlocks  = NPIX * FF / (256 * 4); // 6144
    const int finBlocks  = NPIX / 64;             // 3072
    const int sortBlocks = NPIX / 256;            // 768

    if (useSorted) {
        sort_edges<8><<<sortBlocks, 256, 0, stream>>>(idx1, w1nb, edges1);
        sort_edges<20><<<sortBlocks, 256, 0, stream>>>(idx2, w2nb, edges2);
    }

    // ---------------- layer 1: K=6, NB=8 ----------------
    f2b_kernel<<<cvtBlocks, 256, 0, stream>>>(maps, A);   // A0
    if (useSorted) {
        cheb_stepC<8, 2, true><<<stepBlocks, 256, 0, stream>>>(A, nullptr, A + SLOT, edges1);
        cheb_stepC<8, 2, false><<<stepBlocks, 256, 0, stream>>>(A + SLOT,     A,            A + 2 * SLOT, edges1);
        cheb_stepC<8, 2, false><<<stepBlocks, 256, 0, stream>>>(A + 2 * SLOT, A + SLOT,     A + 3 * SLOT, edges1);
        cheb_stepC<8, 2, false><<<stepBlocks, 256, 0, stream>>>(A + 3 * SLOT, A + 2 * SLOT, A + 4 * SLOT, edges1);
        cheb_stepC<8, 2, false><<<stepBlocks, 256, 0, stream>>>(A + 4 * SLOT, A + 3 * SLOT, A + 5 * SLOT, edges1);
    } else {
        cheb_step4<8, true><<<stepBlocks, 256, 0, stream>>>(A, nullptr, A + SLOT, idx1, w1nb);
        cheb_step4<8, false><<<stepBlocks, 256, 0, stream>>>(A + SLOT,     A,            A + 2 * SLOT, idx1, w1nb);
        cheb_step4<8, false><<<stepBlocks, 256, 0, stream>>>(A + 2 * SLOT, A + SLOT,     A + 3 * SLOT, idx1, w1nb);
        cheb_step4<8, false><<<stepBlocks, 256, 0, stream>>>(A + 3 * SLOT, A + 2 * SLOT, A + 4 * SLOT, idx1, w1nb);
        cheb_step4<8, false><<<stepBlocks, 256, 0, stream>>>(A + 4 * SLOT, A + 3 * SLOT, A + 5 * SLOT, idx1, w1nb);
    }
    finish_gemm<6, false, true><<<finBlocks, 256, 0, stream>>>(A, wd1, wp1, b1, g1, be1, nullptr, B);  // -> B0

    // ---------------- layer 2: K=10, NB=20 ----------------
    if (useSorted) {
        cheb_stepC<20, 5, true><<<stepBlocks, 256, 0, stream>>>(B, nullptr, B + SLOT, edges2);
        for (int k = 2; k <= 9; ++k)
            cheb_stepC<20, 5, false><<<stepBlocks, 256, 0, stream>>>(
                B + (size_t)(k - 1) * SLOT, B + (size_t)(k - 2) * SLOT,
                B + (size_t)k * SLOT, edges2);
    } else {
        cheb_step4<20, true><<<stepBlocks, 256, 0, stream>>>(B, nullptr, B + SLOT, idx2, w2nb);
        for (int k = 2; k <= 9; ++k)
            cheb_step4<20, false><<<stepBlocks, 256, 0, stream>>>(
                B + (size_t)(k - 1) * SLOT, B + (size_t)(k - 2) * SLOT,
                B + (size_t)k * SLOT, idx2, w2nb);
    }
    finish_gemm<10, true, false><<<finBlocks, 256, 0, stream>>>(B, wd2, wp2, b2, g2, be2, maps, out);
}